// Round 1
// baseline (1707.443 us; speedup 1.0000x reference)
//
#include <hip/hip_runtime.h>
#include <hip/hip_bf16.h>

#define N_NODES 40000
#define N_EDGES 640000
#define F_IN    1300
#define NH      4
#define NC      64
#define F_OUT   256   // NH*NC
#define NG      64
#define NEG_SLOPE 0.2f

__device__ __forceinline__ float lrelu(float x) { return x >= 0.f ? x : NEG_SLOPE * x; }

// ---------------------------------------------------------------------------
// GEMM: C[N_NODES, 256] = A[N_NODES, K] @ B[K, 256]   (f32 vector ALU)
// tile 64x64, K-tile 16, 256 threads, 4x4 per thread
// ---------------------------------------------------------------------------
#define BM 64
#define BN 64
#define BK 16
__global__ __launch_bounds__(256) void gemm_kernel(const float* __restrict__ A,
                                                   const float* __restrict__ B,
                                                   float* __restrict__ C, int K)
{
    __shared__ float As[BK][BM + 1];
    __shared__ float Bs[BK][BN];
    const int t  = threadIdx.x;
    const int bm = blockIdx.x * BM;
    const int bn = blockIdx.y * BN;
    const int tx = t & 15;        // col group
    const int ty = t >> 4;        // row group
    const int arow = t >> 2;      // 0..63
    const int akb  = (t & 3) << 2;// 0,4,8,12
    const int bcol = t & 63;
    const int bk0  = t >> 6;      // 0..3

    float acc[4][4] = {};

    for (int k0 = 0; k0 < K; k0 += BK) {
        // A tile: 64 rows x 16 k (float4 per thread, K%4==0 so aligned)
        float4 av = make_float4(0.f, 0.f, 0.f, 0.f);
        if (k0 + akb < K)
            av = *reinterpret_cast<const float4*>(&A[(size_t)(bm + arow) * K + k0 + akb]);
        As[akb + 0][arow] = av.x;
        As[akb + 1][arow] = av.y;
        As[akb + 2][arow] = av.z;
        As[akb + 3][arow] = av.w;
        // B tile: 16 k x 64 cols
#pragma unroll
        for (int p = 0; p < 4; ++p) {
            int kk = bk0 + p * 4;
            float bv = 0.f;
            if (k0 + kk < K) bv = B[(size_t)(k0 + kk) * F_OUT + bn + bcol];
            Bs[kk][bcol] = bv;
        }
        __syncthreads();
#pragma unroll
        for (int kk = 0; kk < BK; ++kk) {
            float a[4], b[4];
#pragma unroll
            for (int i = 0; i < 4; ++i) a[i] = As[kk][ty * 4 + i];
#pragma unroll
            for (int j = 0; j < 4; ++j) b[j] = Bs[kk][tx * 4 + j];
#pragma unroll
            for (int i = 0; i < 4; ++i)
#pragma unroll
                for (int j = 0; j < 4; ++j) acc[i][j] += a[i] * b[j];
        }
        __syncthreads();
    }
#pragma unroll
    for (int i = 0; i < 4; ++i) {
        float4 v = make_float4(acc[i][0], acc[i][1], acc[i][2], acc[i][3]);
        *reinterpret_cast<float4*>(&C[(size_t)(bm + ty * 4 + i) * F_OUT + bn + tx * 4]) = v;
    }
}

// ---------------------------------------------------------------------------
// attention coefficients: a_src[n][h] = sum_c h[n][h*64+c]*att_src[h][c]
// one block (256 thr) per node, wave w handles head w
// ---------------------------------------------------------------------------
__global__ __launch_bounds__(256) void attn_coef_kernel(const float* __restrict__ h,
                                                        const float* __restrict__ att_s,
                                                        const float* __restrict__ att_d,
                                                        float* __restrict__ a_s,
                                                        float* __restrict__ a_d)
{
    const int n = blockIdx.x;
    const int t = threadIdx.x;
    const int w = t >> 6;
    const int l = t & 63;
    float hv = h[(size_t)n * F_OUT + t];
    float vs = hv * att_s[t];
    float vd = hv * att_d[t];
#pragma unroll
    for (int o = 1; o < 64; o <<= 1) {
        vs += __shfl_xor(vs, o);
        vd += __shfl_xor(vd, o);
    }
    if (l == 0) {
        a_s[n * NH + w] = vs;
        a_d[n * NH + w] = vd;
    }
}

// ---------------------------------------------------------------------------
// CSR build (by destination)
// ---------------------------------------------------------------------------
__global__ void hist_kernel(const int* __restrict__ ei, int* __restrict__ deg)
{
    int e = blockIdx.x * blockDim.x + threadIdx.x;
    if (e < N_EDGES) atomicAdd(&deg[ei[N_EDGES + e]], 1);
}

__global__ __launch_bounds__(1024) void scan_kernel(const int* __restrict__ deg,
                                                    int* __restrict__ rowptr)
{
    __shared__ int sums[1024];
    const int t = threadIdx.x;
    const int chunk = (N_NODES + 1023) / 1024;
    int beg = t * chunk;
    int end = beg + chunk; if (end > N_NODES) end = N_NODES;
    if (beg > N_NODES) beg = N_NODES;
    int s = 0;
    for (int i = beg; i < end; ++i) s += deg[i];
    sums[t] = s;
    __syncthreads();
    for (int o = 1; o < 1024; o <<= 1) {
        int v = (t >= o) ? sums[t - o] : 0;
        __syncthreads();
        sums[t] += v;
        __syncthreads();
    }
    int run = (t == 0) ? 0 : sums[t - 1];
    for (int i = beg; i < end; ++i) { rowptr[i] = run; run += deg[i]; }
    if (t == 1023) rowptr[N_NODES] = run;
}

__global__ void scatter_kernel(const int* __restrict__ ei, int* __restrict__ cursor,
                               int* __restrict__ ssrc)
{
    int e = blockIdx.x * blockDim.x + threadIdx.x;
    if (e < N_EDGES) {
        int d = ei[N_EDGES + e];
        int pos = atomicAdd(&cursor[d], 1);
        ssrc[pos] = ei[e];
    }
}

// ---------------------------------------------------------------------------
// GAT aggregation: per destination node: segment max, exp-sum, weighted gather.
// block = 256 threads (4 waves); waves handle heads in phases 1-2;
// all 256 threads accumulate the 256 output channels in phase 3.
// out = relu(agg + bias)
// ---------------------------------------------------------------------------
__global__ __launch_bounds__(256) void agg_kernel(const float* __restrict__ h,
                                                  const float* __restrict__ a_s,
                                                  const float* __restrict__ a_d,
                                                  const int* __restrict__ rowptr,
                                                  const int* __restrict__ ssrc,
                                                  const float* __restrict__ bias,
                                                  float* __restrict__ out)
{
    const int n = blockIdx.x;
    const int t = threadIdx.x;
    const int w = t >> 6;
    const int l = t & 63;
    const int beg = rowptr[n];
    const int deg = rowptr[n + 1] - beg;

    __shared__ float m_s[NH], d_s[NH];

    const float adn = a_d[n * NH + w];
    const float self_e = lrelu(a_s[n * NH + w] + adn);

    // phase 1: max (incl. self loop)
    float mx = self_e;
    for (int i = l; i < deg; i += 64) {
        int s = ssrc[beg + i];
        mx = fmaxf(mx, lrelu(a_s[s * NH + w] + adn));
    }
#pragma unroll
    for (int o = 1; o < 64; o <<= 1) mx = fmaxf(mx, __shfl_xor(mx, o));

    // phase 2: sum of exp
    float sm = (l == 0) ? expf(self_e - mx) : 0.f;
    for (int i = l; i < deg; i += 64) {
        int s = ssrc[beg + i];
        sm += expf(lrelu(a_s[s * NH + w] + adn) - mx);
    }
#pragma unroll
    for (int o = 1; o < 64; o <<= 1) sm += __shfl_xor(sm, o);

    if (l == 0) { m_s[w] = mx; d_s[w] = sm; }
    __syncthreads();

    // phase 3: weighted accumulation over channels (thread t = channel t, head w)
    const float m   = m_s[w];
    const float den = d_s[w] + 1e-16f;
    float acc = expf(self_e - m) / den * h[(size_t)n * F_OUT + t];
    for (int i = 0; i < deg; ++i) {
        int s = ssrc[beg + i];
        float alpha = expf(lrelu(a_s[s * NH + w] + adn) - m) / den;
        acc += alpha * h[(size_t)s * F_OUT + t];
    }
    out[(size_t)n * F_OUT + t] = fmaxf(acc + bias[t], 0.f);
}

// ---------------------------------------------------------------------------
// graph histogram + fused mean-pool + linear head
// ---------------------------------------------------------------------------
__global__ void ghist_kernel(const int* __restrict__ batch, int* __restrict__ gcnt)
{
    int n = blockIdx.x * blockDim.x + threadIdx.x;
    if (n < N_NODES) atomicAdd(&gcnt[batch[n]], 1);
}

__global__ __launch_bounds__(256) void pool_kernel(const float* __restrict__ x,
                                                   const int* __restrict__ gcnt,
                                                   const float* __restrict__ lin_w,
                                                   const float* __restrict__ lin_b,
                                                   float* __restrict__ out)
{
    const int g = blockIdx.x;
    const int t = threadIdx.x;
    __shared__ int s_start;
    if (t == 0) {
        int s = 0;
        for (int i = 0; i < g; ++i) s += gcnt[i];
        s_start = s;
    }
    __syncthreads();
    const int start = s_start;
    const int cnt = gcnt[g];
    float acc = 0.f;
    for (int i = 0; i < cnt; ++i) acc += x[(size_t)(start + i) * F_OUT + t];
    float p = acc / fmaxf((float)cnt, 1.f);
    float v = p * lin_w[t];
    __shared__ float red[256];
    red[t] = v;
    __syncthreads();
    for (int o = 128; o > 0; o >>= 1) {
        if (t < o) red[t] += red[t + o];
        __syncthreads();
    }
    if (t == 0) out[g] = red[0] + lin_b[0];
}

// ---------------------------------------------------------------------------
extern "C" void kernel_launch(void* const* d_in, const int* in_sizes, int n_in,
                              void* d_out, int out_size, void* d_ws, size_t ws_size,
                              hipStream_t stream)
{
    const float* x      = (const float*)d_in[0];
    const int*   ei     = (const int*)  d_in[1];
    const int*   batch  = (const int*)  d_in[2];
    const float* W1     = (const float*)d_in[3];
    const float* att_s1 = (const float*)d_in[4];
    const float* att_d1 = (const float*)d_in[5];
    const float* b1     = (const float*)d_in[6];
    const float* W2     = (const float*)d_in[7];
    const float* att_s2 = (const float*)d_in[8];
    const float* att_d2 = (const float*)d_in[9];
    const float* b2     = (const float*)d_in[10];
    const float* lin_w  = (const float*)d_in[11];
    const float* lin_b  = (const float*)d_in[12];
    float* out = (float*)d_out;

    // workspace carve
    size_t off = 0;
    auto carve = [&](size_t bytes) -> void* {
        void* p = (char*)d_ws + off;
        off += (bytes + 255) & ~(size_t)255;
        return p;
    };
    float* hA     = (float*)carve((size_t)N_NODES * F_OUT * 4);
    float* hB     = (float*)carve((size_t)N_NODES * F_OUT * 4);
    float* a_s    = (float*)carve((size_t)N_NODES * NH * 4);
    float* a_d    = (float*)carve((size_t)N_NODES * NH * 4);
    int*   deg    = (int*)  carve((size_t)(N_NODES + 1) * 4);
    int*   rowptr = (int*)  carve((size_t)(N_NODES + 1) * 4);
    int*   cursor = (int*)  carve((size_t)N_NODES * 4);
    int*   ssrc   = (int*)  carve((size_t)N_EDGES * 4);
    int*   gcnt   = (int*)  carve((size_t)NG * 4);
    (void)ws_size; (void)n_in; (void)in_sizes; (void)out_size;

    // ---- CSR build (edges identical for both layers) ----
    hipMemsetAsync(deg, 0, (size_t)(N_NODES + 1) * 4, stream);
    hipMemsetAsync(gcnt, 0, (size_t)NG * 4, stream);
    hist_kernel<<<(N_EDGES + 255) / 256, 256, 0, stream>>>(ei, deg);
    scan_kernel<<<1, 1024, 0, stream>>>(deg, rowptr);
    hipMemcpyAsync(cursor, rowptr, (size_t)N_NODES * 4, hipMemcpyDeviceToDevice, stream);
    scatter_kernel<<<(N_EDGES + 255) / 256, 256, 0, stream>>>(ei, cursor, ssrc);
    ghist_kernel<<<(N_NODES + 255) / 256, 256, 0, stream>>>(batch, gcnt);

    dim3 ggrid(N_NODES / BM, F_OUT / BN);

    // ---- layer 1 ----
    gemm_kernel<<<ggrid, 256, 0, stream>>>(x, W1, hA, F_IN);
    attn_coef_kernel<<<N_NODES, 256, 0, stream>>>(hA, att_s1, att_d1, a_s, a_d);
    agg_kernel<<<N_NODES, 256, 0, stream>>>(hA, a_s, a_d, rowptr, ssrc, b1, hB);

    // ---- layer 2 ----
    gemm_kernel<<<ggrid, 256, 0, stream>>>(hB, W2, hA, F_OUT);
    attn_coef_kernel<<<N_NODES, 256, 0, stream>>>(hA, att_s2, att_d2, a_s, a_d);
    agg_kernel<<<N_NODES, 256, 0, stream>>>(hA, a_s, a_d, rowptr, ssrc, b2, hB);

    // ---- pool + head ----
    pool_kernel<<<NG, 256, 0, stream>>>(hB, gcnt, lin_w, lin_b, out);
}

// Round 4
// 1234.562 us; speedup vs baseline: 1.3830x; 1.3830x over previous
//
#include <hip/hip_runtime.h>
#include <hip/hip_bf16.h>

#define N_NODES 40000
#define N_EDGES 640000
#define F_IN    1300
#define NH      4
#define NC      64
#define F_OUT   256   // NH*NC
#define NG      64
#define NEG_SLOPE 0.2f

typedef short short8v __attribute__((ext_vector_type(8)));
typedef float f32x16  __attribute__((ext_vector_type(16)));

__device__ __forceinline__ float lrelu(float x) { return x >= 0.f ? x : NEG_SLOPE * x; }

// bf16 round-to-nearest-even split helpers
__device__ __forceinline__ short f2bf(float v) {
    unsigned u = __builtin_bit_cast(unsigned, v);
    unsigned r = (u + 0x7fffu + ((u >> 16) & 1u)) >> 16;
    return (short)r;
}
__device__ __forceinline__ float bf2f(short s) {
    unsigned u = ((unsigned)(unsigned short)s) << 16;
    return __builtin_bit_cast(float, u);
}

__device__ __forceinline__ short8v ld8(const short* p) {
    short4 a = *(const short4*)(p);
    short4 b = *(const short4*)(p + 4);
    short8v r;
    r[0] = a.x; r[1] = a.y; r[2] = a.z; r[3] = a.w;
    r[4] = b.x; r[5] = b.y; r[6] = b.z; r[7] = b.w;
    return r;
}

// ---------------------------------------------------------------------------
// W pre-split: Wt_hi/Wt_lo[n][k] = bf16 split of W[k][n], k padded to Kp (zeros)
// ---------------------------------------------------------------------------
__global__ void wsplit_kernel(const float* __restrict__ W, short* __restrict__ hi,
                              short* __restrict__ lo, int K, int Kp)
{
    int idx = blockIdx.x * 256 + threadIdx.x;
    if (idx >= F_OUT * Kp) return;
    int n = idx / Kp, k = idx - n * Kp;
    float v = (k < K) ? W[(size_t)k * F_OUT + n] : 0.f;
    short h = f2bf(v);
    short l = f2bf(v - bf2f(h));
    hi[idx] = h;
    lo[idx] = l;
}

// ---------------------------------------------------------------------------
// GEMM: C[N_NODES,256] = A[N_NODES,K] @ B[K,256] via bf16x3 MFMA (near-f32 acc)
// BM=64 rows/block, BN=256 (full width), BK=32. 4 waves, each 64x64 (2x2 frags
// of 32x32x16). A converted f32->bf16 hi/lo on the fly; B pre-split (Bt[n][k]).
// ---------------------------------------------------------------------------
#define BK  32
#define LDK 40   // padded LDS row stride (shorts): 80B -> conflict-free b64 reads

__global__ __launch_bounds__(256, 2) void gemm_mfma_kernel(
    const float* __restrict__ A, const short* __restrict__ Bth,
    const short* __restrict__ Btl, float* __restrict__ C, int K, int Kp)
{
    __shared__ short As_hi[64][LDK], As_lo[64][LDK];
    __shared__ short Bs_hi[256][LDK], Bs_lo[256][LDK];

    const int t    = threadIdx.x;
    const int lane = t & 63;
    const int wv   = t >> 6;
    const int wc   = wv * 64;            // wave's column base
    const int bm   = blockIdx.x * 64;

    f32x16 acc[2][2];
#pragma unroll
    for (int i = 0; i < 2; ++i)
#pragma unroll
        for (int j = 0; j < 2; ++j)
#pragma unroll
            for (int r = 0; r < 16; ++r) acc[i][j][r] = 0.f;

    const int arow = t >> 2;             // 0..63
    const int ac   = (t & 3) * 4;        // 0,4,8,12
    const int bko  = (t & 3) * 8;        // 0,8,16,24

    for (int k0 = 0; k0 < Kp; k0 += BK) {
        __syncthreads();
        // stage A: 64 x 32 f32 -> bf16 hi/lo
#pragma unroll
        for (int p = 0; p < 2; ++p) {
            int kk = ac + p * 16;
            int gk = k0 + kk;
            float4 v = make_float4(0.f, 0.f, 0.f, 0.f);
            if (gk < K) v = *(const float4*)&A[(size_t)(bm + arow) * K + gk];
            short4 h4, l4;
            h4.x = f2bf(v.x); l4.x = f2bf(v.x - bf2f(h4.x));
            h4.y = f2bf(v.y); l4.y = f2bf(v.y - bf2f(h4.y));
            h4.z = f2bf(v.z); l4.z = f2bf(v.z - bf2f(h4.z));
            h4.w = f2bf(v.w); l4.w = f2bf(v.w - bf2f(h4.w));
            *(short4*)&As_hi[arow][kk] = h4;
            *(short4*)&As_lo[arow][kk] = l4;
        }
        // stage B: 256 cols x 32 k (already bf16 hi/lo, [col][k] layout)
#pragma unroll
        for (int p = 0; p < 4; ++p) {
            int col = p * 64 + (t >> 2);
            size_t gb = (size_t)col * Kp + k0 + bko;
            short4 h0 = *(const short4*)&Bth[gb];
            short4 h1 = *(const short4*)&Bth[gb + 4];
            short4 l0 = *(const short4*)&Btl[gb];
            short4 l1 = *(const short4*)&Btl[gb + 4];
            *(short4*)&Bs_hi[col][bko]     = h0;
            *(short4*)&Bs_hi[col][bko + 4] = h1;
            *(short4*)&Bs_lo[col][bko]     = l0;
            *(short4*)&Bs_lo[col][bko + 4] = l1;
        }
        __syncthreads();
        // compute: 2 K16-steps x (2x2 frags) x 3 mfma
#pragma unroll
        for (int ks = 0; ks < 2; ++ks) {
            const int ko = ks * 16 + (lane >> 5) * 8;
            const int mr = lane & 31;
            short8v ah0 = ld8(&As_hi[mr][ko]);
            short8v ah1 = ld8(&As_hi[32 + mr][ko]);
            short8v al0 = ld8(&As_lo[mr][ko]);
            short8v al1 = ld8(&As_lo[32 + mr][ko]);
            short8v bh0 = ld8(&Bs_hi[wc + mr][ko]);
            short8v bh1 = ld8(&Bs_hi[wc + 32 + mr][ko]);
            short8v bl0 = ld8(&Bs_lo[wc + mr][ko]);
            short8v bl1 = ld8(&Bs_lo[wc + 32 + mr][ko]);
            acc[0][0] = __builtin_amdgcn_mfma_f32_32x32x16_bf16(ah0, bh0, acc[0][0], 0, 0, 0);
            acc[0][0] = __builtin_amdgcn_mfma_f32_32x32x16_bf16(ah0, bl0, acc[0][0], 0, 0, 0);
            acc[0][0] = __builtin_amdgcn_mfma_f32_32x32x16_bf16(al0, bh0, acc[0][0], 0, 0, 0);
            acc[0][1] = __builtin_amdgcn_mfma_f32_32x32x16_bf16(ah0, bh1, acc[0][1], 0, 0, 0);
            acc[0][1] = __builtin_amdgcn_mfma_f32_32x32x16_bf16(ah0, bl1, acc[0][1], 0, 0, 0);
            acc[0][1] = __builtin_amdgcn_mfma_f32_32x32x16_bf16(al0, bh1, acc[0][1], 0, 0, 0);
            acc[1][0] = __builtin_amdgcn_mfma_f32_32x32x16_bf16(ah1, bh0, acc[1][0], 0, 0, 0);
            acc[1][0] = __builtin_amdgcn_mfma_f32_32x32x16_bf16(ah1, bl0, acc[1][0], 0, 0, 0);
            acc[1][0] = __builtin_amdgcn_mfma_f32_32x32x16_bf16(al1, bh0, acc[1][0], 0, 0, 0);
            acc[1][1] = __builtin_amdgcn_mfma_f32_32x32x16_bf16(ah1, bh1, acc[1][1], 0, 0, 0);
            acc[1][1] = __builtin_amdgcn_mfma_f32_32x32x16_bf16(ah1, bl1, acc[1][1], 0, 0, 0);
            acc[1][1] = __builtin_amdgcn_mfma_f32_32x32x16_bf16(al1, bh1, acc[1][1], 0, 0, 0);
        }
    }
    // epilogue: C/D layout (m74/m101): col=lane&31, row=(r&3)+8*(r>>2)+4*(lane>>5)
#pragma unroll
    for (int fm = 0; fm < 2; ++fm)
#pragma unroll
        for (int fn = 0; fn < 2; ++fn)
#pragma unroll
            for (int r = 0; r < 16; ++r) {
                int row = bm + fm * 32 + (r & 3) + 8 * (r >> 2) + 4 * (lane >> 5);
                int col = wc + fn * 32 + (lane & 31);
                C[(size_t)row * F_OUT + col] = acc[fm][fn][r];
            }
}

// ---------------------------------------------------------------------------
// attention coefficients
// ---------------------------------------------------------------------------
__global__ __launch_bounds__(256) void attn_coef_kernel(const float* __restrict__ h,
                                                        const float* __restrict__ att_s,
                                                        const float* __restrict__ att_d,
                                                        float* __restrict__ a_s,
                                                        float* __restrict__ a_d)
{
    const int n = blockIdx.x;
    const int t = threadIdx.x;
    const int w = t >> 6;
    const int l = t & 63;
    float hv = h[(size_t)n * F_OUT + t];
    float vs = hv * att_s[t];
    float vd = hv * att_d[t];
#pragma unroll
    for (int o = 1; o < 64; o <<= 1) {
        vs += __shfl_xor(vs, o);
        vd += __shfl_xor(vd, o);
    }
    if (l == 0) {
        a_s[n * NH + w] = vs;
        a_d[n * NH + w] = vd;
    }
}

// ---------------------------------------------------------------------------
// CSR build (by destination)
// ---------------------------------------------------------------------------
__global__ void hist_kernel(const int* __restrict__ ei, int* __restrict__ deg)
{
    int e = blockIdx.x * blockDim.x + threadIdx.x;
    if (e < N_EDGES) atomicAdd(&deg[ei[N_EDGES + e]], 1);
}

__global__ __launch_bounds__(1024) void scan_kernel(const int* __restrict__ deg,
                                                    int* __restrict__ rowptr)
{
    __shared__ int sums[1024];
    const int t = threadIdx.x;
    const int chunk = (N_NODES + 1023) / 1024;
    int beg = t * chunk;
    int end = beg + chunk; if (end > N_NODES) end = N_NODES;
    if (beg > N_NODES) beg = N_NODES;
    int s = 0;
    for (int i = beg; i < end; ++i) s += deg[i];
    sums[t] = s;
    __syncthreads();
    for (int o = 1; o < 1024; o <<= 1) {
        int v = (t >= o) ? sums[t - o] : 0;
        __syncthreads();
        sums[t] += v;
        __syncthreads();
    }
    int run = (t == 0) ? 0 : sums[t - 1];
    for (int i = beg; i < end; ++i) { rowptr[i] = run; run += deg[i]; }
    if (t == 1023) rowptr[N_NODES] = run;
}

__global__ void scatter_kernel(const int* __restrict__ ei, int* __restrict__ cursor,
                               int* __restrict__ ssrc)
{
    int e = blockIdx.x * blockDim.x + threadIdx.x;
    if (e < N_EDGES) {
        int d = ei[N_EDGES + e];
        int pos = atomicAdd(&cursor[d], 1);
        ssrc[pos] = ei[e];
    }
}

// ---------------------------------------------------------------------------
// GAT aggregation: segment softmax + weighted gather, chunked with LDS alphas
// ---------------------------------------------------------------------------
__global__ __launch_bounds__(256) void agg_kernel(const float* __restrict__ h,
                                                  const float* __restrict__ a_s,
                                                  const float* __restrict__ a_d,
                                                  const int* __restrict__ rowptr,
                                                  const int* __restrict__ ssrc,
                                                  const float* __restrict__ bias,
                                                  float* __restrict__ out)
{
    const int n = blockIdx.x;
    const int t = threadIdx.x;
    const int w = t >> 6;
    const int l = t & 63;
    const int beg = rowptr[n];
    const int deg = rowptr[n + 1] - beg;

    __shared__ float m_s[NH], d_s[NH];
    __shared__ int   s_idx[64];
    __shared__ float s_alpha[64][NH];

    const float adn    = a_d[n * NH + w];
    const float self_e = lrelu(a_s[n * NH + w] + adn);

    // phase 1: segment max (wave w = head w)
    float mx = self_e;
    for (int i = l; i < deg; i += 64) {
        int s = ssrc[beg + i];
        mx = fmaxf(mx, lrelu(a_s[s * NH + w] + adn));
    }
#pragma unroll
    for (int o = 1; o < 64; o <<= 1) mx = fmaxf(mx, __shfl_xor(mx, o));

    // phase 2: sum of exp
    float sm = (l == 0) ? expf(self_e - mx) : 0.f;
    for (int i = l; i < deg; i += 64) {
        int s = ssrc[beg + i];
        sm += expf(lrelu(a_s[s * NH + w] + adn) - mx);
    }
#pragma unroll
    for (int o = 1; o < 64; o <<= 1) sm += __shfl_xor(sm, o);

    if (l == 0) { m_s[w] = mx; d_s[w] = sm; }
    __syncthreads();

    // phase 3: weighted accumulation, 64-edge chunks with precomputed alphas
    const float m   = m_s[w];
    const float den = d_s[w] + 1e-16f;
    float acc = expf(self_e - m) / den * h[(size_t)n * F_OUT + t];

    for (int base = 0; base < deg; base += 64) {
        int cnt = deg - base; if (cnt > 64) cnt = 64;
        if (l < cnt) {
            int s = ssrc[beg + base + l];
            if (w == 0) s_idx[l] = s;
            s_alpha[l][w] = expf(lrelu(a_s[s * NH + w] + adn) - m) / den;
        }
        __syncthreads();
        int i = 0;
        int c4 = cnt & ~3;
        for (; i < c4; i += 4) {
            int   s0 = s_idx[i],     s1 = s_idx[i + 1];
            int   s2 = s_idx[i + 2], s3 = s_idx[i + 3];
            float a0 = s_alpha[i][w],     a1 = s_alpha[i + 1][w];
            float a2 = s_alpha[i + 2][w], a3 = s_alpha[i + 3][w];
            float h0 = h[(size_t)s0 * F_OUT + t];
            float h1 = h[(size_t)s1 * F_OUT + t];
            float h2 = h[(size_t)s2 * F_OUT + t];
            float h3 = h[(size_t)s3 * F_OUT + t];
            acc += a0 * h0 + a1 * h1 + a2 * h2 + a3 * h3;
        }
        for (; i < cnt; ++i)
            acc += s_alpha[i][w] * h[(size_t)s_idx[i] * F_OUT + t];
        __syncthreads();
    }
    out[(size_t)n * F_OUT + t] = fmaxf(acc + bias[t], 0.f);
}

// ---------------------------------------------------------------------------
// graph histogram + fused mean-pool + linear head
// ---------------------------------------------------------------------------
__global__ void ghist_kernel(const int* __restrict__ batch, int* __restrict__ gcnt)
{
    int n = blockIdx.x * blockDim.x + threadIdx.x;
    if (n < N_NODES) atomicAdd(&gcnt[batch[n]], 1);
}

__global__ __launch_bounds__(256) void pool_kernel(const float* __restrict__ x,
                                                   const int* __restrict__ gcnt,
                                                   const float* __restrict__ lin_w,
                                                   const float* __restrict__ lin_b,
                                                   float* __restrict__ out)
{
    const int g = blockIdx.x;
    const int t = threadIdx.x;
    __shared__ int s_start;
    if (t == 0) {
        int s = 0;
        for (int i = 0; i < g; ++i) s += gcnt[i];
        s_start = s;
    }
    __syncthreads();
    const int start = s_start;
    const int cnt = gcnt[g];
    float acc = 0.f;
    for (int i = 0; i < cnt; ++i) acc += x[(size_t)(start + i) * F_OUT + t];
    float p = acc / fmaxf((float)cnt, 1.f);
    float v = p * lin_w[t];
    __shared__ float red[256];
    red[t] = v;
    __syncthreads();
    for (int o = 128; o > 0; o >>= 1) {
        if (t < o) red[t] += red[t + o];
        __syncthreads();
    }
    if (t == 0) out[g] = red[0] + lin_b[0];
}

// ---------------------------------------------------------------------------
extern "C" void kernel_launch(void* const* d_in, const int* in_sizes, int n_in,
                              void* d_out, int out_size, void* d_ws, size_t ws_size,
                              hipStream_t stream)
{
    const float* x      = (const float*)d_in[0];
    const int*   ei     = (const int*)  d_in[1];
    const int*   batch  = (const int*)  d_in[2];
    const float* W1     = (const float*)d_in[3];
    const float* att_s1 = (const float*)d_in[4];
    const float* att_d1 = (const float*)d_in[5];
    const float* b1     = (const float*)d_in[6];
    const float* W2     = (const float*)d_in[7];
    const float* att_s2 = (const float*)d_in[8];
    const float* att_d2 = (const float*)d_in[9];
    const float* b2     = (const float*)d_in[10];
    const float* lin_w  = (const float*)d_in[11];
    const float* lin_b  = (const float*)d_in[12];
    float* out = (float*)d_out;

    const int Kp1 = 1312;   // 1300 padded to x32
    const int Kp2 = 256;

    size_t off = 0;
    auto carve = [&](size_t bytes) -> void* {
        void* p = (char*)d_ws + off;
        off += (bytes + 255) & ~(size_t)255;
        return p;
    };
    float* hA     = (float*)carve((size_t)N_NODES * F_OUT * 4);
    float* hB     = (float*)carve((size_t)N_NODES * F_OUT * 4);
    float* a_s    = (float*)carve((size_t)N_NODES * NH * 4);
    float* a_d    = (float*)carve((size_t)N_NODES * NH * 4);
    int*   deg    = (int*)  carve((size_t)(N_NODES + 1) * 4);
    int*   rowptr = (int*)  carve((size_t)(N_NODES + 1) * 4);
    int*   cursor = (int*)  carve((size_t)N_NODES * 4);
    int*   ssrc   = (int*)  carve((size_t)N_EDGES * 4);
    int*   gcnt   = (int*)  carve((size_t)NG * 4);
    short* Bt1h   = (short*)carve((size_t)F_OUT * Kp1 * 2);
    short* Bt1l   = (short*)carve((size_t)F_OUT * Kp1 * 2);
    short* Bt2h   = (short*)carve((size_t)F_OUT * Kp2 * 2);
    short* Bt2l   = (short*)carve((size_t)F_OUT * Kp2 * 2);
    (void)ws_size; (void)n_in; (void)in_sizes; (void)out_size;

    // ---- CSR build + weight pre-split ----
    hipMemsetAsync(deg, 0, (size_t)(N_NODES + 1) * 4, stream);
    hipMemsetAsync(gcnt, 0, (size_t)NG * 4, stream);
    hist_kernel<<<(N_EDGES + 255) / 256, 256, 0, stream>>>(ei, deg);
    scan_kernel<<<1, 1024, 0, stream>>>(deg, rowptr);
    hipMemcpyAsync(cursor, rowptr, (size_t)N_NODES * 4, hipMemcpyDeviceToDevice, stream);
    scatter_kernel<<<(N_EDGES + 255) / 256, 256, 0, stream>>>(ei, cursor, ssrc);
    ghist_kernel<<<(N_NODES + 255) / 256, 256, 0, stream>>>(batch, gcnt);
    wsplit_kernel<<<(F_OUT * Kp1 + 255) / 256, 256, 0, stream>>>(W1, Bt1h, Bt1l, F_IN, Kp1);
    wsplit_kernel<<<(F_OUT * Kp2 + 255) / 256, 256, 0, stream>>>(W2, Bt2h, Bt2l, F_OUT, Kp2);

    const int gblocks = N_NODES / 64;  // 625

    // ---- layer 1 ----
    gemm_mfma_kernel<<<gblocks, 256, 0, stream>>>(x, Bt1h, Bt1l, hA, F_IN, Kp1);
    attn_coef_kernel<<<N_NODES, 256, 0, stream>>>(hA, att_s1, att_d1, a_s, a_d);
    agg_kernel<<<N_NODES, 256, 0, stream>>>(hA, a_s, a_d, rowptr, ssrc, b1, hB);

    // ---- layer 2 ----
    gemm_mfma_kernel<<<gblocks, 256, 0, stream>>>(hB, Bt2h, Bt2l, hA, F_OUT, Kp2);
    attn_coef_kernel<<<N_NODES, 256, 0, stream>>>(hA, att_s2, att_d2, a_s, a_d);
    agg_kernel<<<N_NODES, 256, 0, stream>>>(hA, a_s, a_d, rowptr, ssrc, b2, hB);

    // ---- pool + head ----
    pool_kernel<<<NG, 256, 0, stream>>>(hB, gcnt, lin_w, lin_b, out);
}

// Round 5
// 1183.316 us; speedup vs baseline: 1.4429x; 1.0433x over previous
//
#include <hip/hip_runtime.h>
#include <hip/hip_bf16.h>

#define N_NODES 40000
#define N_EDGES 640000
#define F_IN    1300
#define NH      4
#define NC      64
#define F_OUT   256   // NH*NC
#define NG      64
#define NEG_SLOPE 0.2f

typedef short short8v __attribute__((ext_vector_type(8)));
typedef float f32x16  __attribute__((ext_vector_type(16)));

__device__ __forceinline__ float lrelu(float x) { return x >= 0.f ? x : NEG_SLOPE * x; }

// bf16 round-to-nearest-even split helpers
__device__ __forceinline__ short f2bf(float v) {
    unsigned u = __builtin_bit_cast(unsigned, v);
    unsigned r = (u + 0x7fffu + ((u >> 16) & 1u)) >> 16;
    return (short)r;
}
__device__ __forceinline__ float bf2f(short s) {
    unsigned u = ((unsigned)(unsigned short)s) << 16;
    return __builtin_bit_cast(float, u);
}

__device__ __forceinline__ short8v ld8(const short* p) {
    short4 a = *(const short4*)(p);
    short4 b = *(const short4*)(p + 4);
    short8v r;
    r[0] = a.x; r[1] = a.y; r[2] = a.z; r[3] = a.w;
    r[4] = b.x; r[5] = b.y; r[6] = b.z; r[7] = b.w;
    return r;
}

// ---------------------------------------------------------------------------
// W pre-split: Wt_hi/Wt_lo[n][k] = bf16 split of W[k][n], k padded to Kp (zeros)
// ---------------------------------------------------------------------------
__global__ void wsplit_kernel(const float* __restrict__ W, short* __restrict__ hi,
                              short* __restrict__ lo, int K, int Kp)
{
    int idx = blockIdx.x * 256 + threadIdx.x;
    if (idx >= F_OUT * Kp) return;
    int n = idx / Kp, k = idx - n * Kp;
    float v = (k < K) ? W[(size_t)k * F_OUT + n] : 0.f;
    short h = f2bf(v);
    short l = f2bf(v - bf2f(h));
    hi[idx] = h;
    lo[idx] = l;
}

// ---------------------------------------------------------------------------
// GEMM v2: C[N,256] = A[N,K] @ B[K,256], bf16x3 MFMA.
// A: staged to LDS (hi/lo, double-buffered, LDK=36 -> 2-way-free bank pattern),
//    converted f32->bf16 on the fly, software-pipelined (prefetch t+1).
// B: pre-split bf16 [col][k], L2-resident (1.3MB) -> fragments loaded straight
//    from global into registers each iter; NO B LDS staging.
// One barrier per K-iter. 4 waves, each 64 rows x 64 cols (2x2 32x32x16 frags).
// ---------------------------------------------------------------------------
#define BK  32
#define LDK 36   // row stride in shorts: 72B, gcd(72,128)=8 -> 2-way (free)

__global__ __launch_bounds__(256, 3) void gemm_mfma_kernel(
    const float* __restrict__ A, const short* __restrict__ Bth,
    const short* __restrict__ Btl, float* __restrict__ C, int K, int Kp)
{
    __shared__ short As_hi[2][64][LDK];
    __shared__ short As_lo[2][64][LDK];

    const int t    = threadIdx.x;
    const int lane = t & 63;
    const int wv   = t >> 6;
    const int wc   = wv * 64;            // wave's column base
    const int bm   = blockIdx.x * 64;

    f32x16 acc[2][2];
#pragma unroll
    for (int i = 0; i < 2; ++i)
#pragma unroll
        for (int j = 0; j < 2; ++j)
#pragma unroll
            for (int r = 0; r < 16; ++r) acc[i][j][r] = 0.f;

    const int arow = t >> 2;             // 0..63
    const int ac   = (t & 3) * 4;        // 0,4,8,12 (+16 for p=1)
    const int mr   = lane & 31;
    const int khalf = (lane >> 5) * 8;   // 0 or 8

    const size_t abase = (size_t)(bm + arow) * K;
    // B fragment pointers (per-lane, constant across K-iters except k0)
    const size_t b0 = (size_t)(wc + mr) * Kp + khalf;        // frag col 0..31
    const size_t b1 = (size_t)(wc + 32 + mr) * Kp + khalf;   // frag col 32..63

    const int nt = Kp / BK;

    // ---- prologue: prefetch A tile 0 into regs ----
    float4 av0 = make_float4(0.f, 0.f, 0.f, 0.f);
    float4 av1 = make_float4(0.f, 0.f, 0.f, 0.f);
    if (ac < K)      av0 = *(const float4*)&A[abase + ac];
    if (ac + 16 < K) av1 = *(const float4*)&A[abase + ac + 16];

    for (int it = 0; it < nt; ++it) {
        const int k0  = it * BK;
        const int buf = it & 1;

        // ---- issue B fragment loads for this iter (global, L2-hit) ----
        const short8v bh0_0 = *(const short8v*)&Bth[b0 + k0];
        const short8v bh0_1 = *(const short8v*)&Bth[b0 + k0 + 16];
        const short8v bh1_0 = *(const short8v*)&Bth[b1 + k0];
        const short8v bh1_1 = *(const short8v*)&Bth[b1 + k0 + 16];
        const short8v bl0_0 = *(const short8v*)&Btl[b0 + k0];
        const short8v bl0_1 = *(const short8v*)&Btl[b0 + k0 + 16];
        const short8v bl1_0 = *(const short8v*)&Btl[b1 + k0];
        const short8v bl1_1 = *(const short8v*)&Btl[b1 + k0 + 16];

        // ---- convert + write A tile `it` to LDS buf ----
        {
            short4 h4, l4;
            h4.x = f2bf(av0.x); l4.x = f2bf(av0.x - bf2f(h4.x));
            h4.y = f2bf(av0.y); l4.y = f2bf(av0.y - bf2f(h4.y));
            h4.z = f2bf(av0.z); l4.z = f2bf(av0.z - bf2f(h4.z));
            h4.w = f2bf(av0.w); l4.w = f2bf(av0.w - bf2f(h4.w));
            *(short4*)&As_hi[buf][arow][ac] = h4;
            *(short4*)&As_lo[buf][arow][ac] = l4;
            h4.x = f2bf(av1.x); l4.x = f2bf(av1.x - bf2f(h4.x));
            h4.y = f2bf(av1.y); l4.y = f2bf(av1.y - bf2f(h4.y));
            h4.z = f2bf(av1.z); l4.z = f2bf(av1.z - bf2f(h4.z));
            h4.w = f2bf(av1.w); l4.w = f2bf(av1.w - bf2f(h4.w));
            *(short4*)&As_hi[buf][arow][ac + 16] = h4;
            *(short4*)&As_lo[buf][arow][ac + 16] = l4;
        }

        // ---- prefetch A tile it+1 into regs ----
        float4 nv0 = make_float4(0.f, 0.f, 0.f, 0.f);
        float4 nv1 = make_float4(0.f, 0.f, 0.f, 0.f);
        if (it + 1 < nt) {
            int gk0 = k0 + BK + ac;
            if (gk0 < K)      nv0 = *(const float4*)&A[abase + gk0];
            if (gk0 + 16 < K) nv1 = *(const float4*)&A[abase + gk0 + 16];
        }

        __syncthreads();   // A tile `it` visible; prev iter's reads already consumed

        // ---- compute: 2 K16-steps x (2x2 frags) x 3 mfma ----
#pragma unroll
        for (int ks = 0; ks < 2; ++ks) {
            const int ko = ks * 16 + khalf;
            short8v ah0 = ld8(&As_hi[buf][mr][ko]);
            short8v ah1 = ld8(&As_hi[buf][32 + mr][ko]);
            short8v al0 = ld8(&As_lo[buf][mr][ko]);
            short8v al1 = ld8(&As_lo[buf][32 + mr][ko]);
            const short8v bh0 = ks ? bh0_1 : bh0_0;
            const short8v bh1 = ks ? bh1_1 : bh1_0;
            const short8v bl0 = ks ? bl0_1 : bl0_0;
            const short8v bl1 = ks ? bl1_1 : bl1_0;
            acc[0][0] = __builtin_amdgcn_mfma_f32_32x32x16_bf16(ah0, bh0, acc[0][0], 0, 0, 0);
            acc[0][0] = __builtin_amdgcn_mfma_f32_32x32x16_bf16(ah0, bl0, acc[0][0], 0, 0, 0);
            acc[0][0] = __builtin_amdgcn_mfma_f32_32x32x16_bf16(al0, bh0, acc[0][0], 0, 0, 0);
            acc[0][1] = __builtin_amdgcn_mfma_f32_32x32x16_bf16(ah0, bh1, acc[0][1], 0, 0, 0);
            acc[0][1] = __builtin_amdgcn_mfma_f32_32x32x16_bf16(ah0, bl1, acc[0][1], 0, 0, 0);
            acc[0][1] = __builtin_amdgcn_mfma_f32_32x32x16_bf16(al0, bh1, acc[0][1], 0, 0, 0);
            acc[1][0] = __builtin_amdgcn_mfma_f32_32x32x16_bf16(ah1, bh0, acc[1][0], 0, 0, 0);
            acc[1][0] = __builtin_amdgcn_mfma_f32_32x32x16_bf16(ah1, bl0, acc[1][0], 0, 0, 0);
            acc[1][0] = __builtin_amdgcn_mfma_f32_32x32x16_bf16(al1, bh0, acc[1][0], 0, 0, 0);
            acc[1][1] = __builtin_amdgcn_mfma_f32_32x32x16_bf16(ah1, bh1, acc[1][1], 0, 0, 0);
            acc[1][1] = __builtin_amdgcn_mfma_f32_32x32x16_bf16(ah1, bl1, acc[1][1], 0, 0, 0);
            acc[1][1] = __builtin_amdgcn_mfma_f32_32x32x16_bf16(al1, bh1, acc[1][1], 0, 0, 0);
        }
        av0 = nv0;
        av1 = nv1;
    }
    // epilogue: C/D layout (m74/m101): col=lane&31, row=(r&3)+8*(r>>2)+4*(lane>>5)
#pragma unroll
    for (int fm = 0; fm < 2; ++fm)
#pragma unroll
        for (int fn = 0; fn < 2; ++fn)
#pragma unroll
            for (int r = 0; r < 16; ++r) {
                int row = bm + fm * 32 + (r & 3) + 8 * (r >> 2) + 4 * (lane >> 5);
                int col = wc + fn * 32 + (lane & 31);
                C[(size_t)row * F_OUT + col] = acc[fm][fn][r];
            }
}

// ---------------------------------------------------------------------------
// attention coefficients
// ---------------------------------------------------------------------------
__global__ __launch_bounds__(256) void attn_coef_kernel(const float* __restrict__ h,
                                                        const float* __restrict__ att_s,
                                                        const float* __restrict__ att_d,
                                                        float* __restrict__ a_s,
                                                        float* __restrict__ a_d)
{
    const int n = blockIdx.x;
    const int t = threadIdx.x;
    const int w = t >> 6;
    const int l = t & 63;
    float hv = h[(size_t)n * F_OUT + t];
    float vs = hv * att_s[t];
    float vd = hv * att_d[t];
#pragma unroll
    for (int o = 1; o < 64; o <<= 1) {
        vs += __shfl_xor(vs, o);
        vd += __shfl_xor(vd, o);
    }
    if (l == 0) {
        a_s[n * NH + w] = vs;
        a_d[n * NH + w] = vd;
    }
}

// ---------------------------------------------------------------------------
// CSR build (by destination)
// ---------------------------------------------------------------------------
__global__ void hist_kernel(const int* __restrict__ ei, int* __restrict__ deg)
{
    int e = blockIdx.x * blockDim.x + threadIdx.x;
    if (e < N_EDGES) atomicAdd(&deg[ei[N_EDGES + e]], 1);
}

__global__ __launch_bounds__(1024) void scan_kernel(const int* __restrict__ deg,
                                                    int* __restrict__ rowptr)
{
    __shared__ int sums[1024];
    const int t = threadIdx.x;
    const int chunk = (N_NODES + 1023) / 1024;
    int beg = t * chunk;
    int end = beg + chunk; if (end > N_NODES) end = N_NODES;
    if (beg > N_NODES) beg = N_NODES;
    int s = 0;
    for (int i = beg; i < end; ++i) s += deg[i];
    sums[t] = s;
    __syncthreads();
    for (int o = 1; o < 1024; o <<= 1) {
        int v = (t >= o) ? sums[t - o] : 0;
        __syncthreads();
        sums[t] += v;
        __syncthreads();
    }
    int run = (t == 0) ? 0 : sums[t - 1];
    for (int i = beg; i < end; ++i) { rowptr[i] = run; run += deg[i]; }
    if (t == 1023) rowptr[N_NODES] = run;
}

__global__ void scatter_kernel(const int* __restrict__ ei, int* __restrict__ cursor,
                               int* __restrict__ ssrc)
{
    int e = blockIdx.x * blockDim.x + threadIdx.x;
    if (e < N_EDGES) {
        int d = ei[N_EDGES + e];
        int pos = atomicAdd(&cursor[d], 1);
        ssrc[pos] = ei[e];
    }
}

// ---------------------------------------------------------------------------
// GAT aggregation v2: ONE WAVE PER NODE, no LDS, no block barriers.
// Lanes 16h..16h+15 handle head h for segment max / exp-sum.
// Phase 3: lane l accumulates channels [4l,4l+4) (head l>>4) with float4
// gathers of h[src], 4-deep unrolled for outstanding loads.
// ---------------------------------------------------------------------------
__global__ __launch_bounds__(256) void agg_kernel(const float* __restrict__ h,
                                                  const float* __restrict__ a_s,
                                                  const float* __restrict__ a_d,
                                                  const int* __restrict__ rowptr,
                                                  const int* __restrict__ ssrc,
                                                  const float* __restrict__ bias,
                                                  float* __restrict__ out)
{
    const int wv = threadIdx.x >> 6;
    const int n  = blockIdx.x * 4 + wv;
    const int l  = threadIdx.x & 63;
    const int hd = l >> 4;     // head
    const int g  = l & 15;     // lane in head-group

    const int beg = rowptr[n];
    const int deg = rowptr[n + 1] - beg;

    const float adn    = a_d[n * NH + hd];
    const float self_e = lrelu(a_s[n * NH + hd] + adn);

    // phase 1: segment max (16 lanes per head)
    float mx = self_e;
    for (int i = g; i < deg; i += 16) {
        int s = ssrc[beg + i];
        mx = fmaxf(mx, lrelu(a_s[s * NH + hd] + adn));
    }
#pragma unroll
    for (int o = 1; o < 16; o <<= 1) mx = fmaxf(mx, __shfl_xor(mx, o));

    // phase 2: sum of exp
    float sm = (g == 0) ? expf(self_e - mx) : 0.f;
    for (int i = g; i < deg; i += 16) {
        int s = ssrc[beg + i];
        sm += expf(lrelu(a_s[s * NH + hd] + adn) - mx);
    }
#pragma unroll
    for (int o = 1; o < 16; o <<= 1) sm += __shfl_xor(sm, o);
    const float den = sm + 1e-16f;

    // phase 3: weighted gather, float4 per lane (channels 4l..4l+3)
    const int c0 = l * 4;
    float4 acc;
    {
        float a0 = expf(self_e - mx) / den;
        float4 hv = *(const float4*)&h[(size_t)n * F_OUT + c0];
        acc.x = a0 * hv.x; acc.y = a0 * hv.y; acc.z = a0 * hv.z; acc.w = a0 * hv.w;
    }
    int i = 0;
    for (; i + 4 <= deg; i += 4) {
        int s0 = ssrc[beg + i];
        int s1 = ssrc[beg + i + 1];
        int s2 = ssrc[beg + i + 2];
        int s3 = ssrc[beg + i + 3];
        float e0 = a_s[s0 * NH + hd], e1 = a_s[s1 * NH + hd];
        float e2 = a_s[s2 * NH + hd], e3 = a_s[s3 * NH + hd];
        float4 h0 = *(const float4*)&h[(size_t)s0 * F_OUT + c0];
        float4 h1 = *(const float4*)&h[(size_t)s1 * F_OUT + c0];
        float4 h2 = *(const float4*)&h[(size_t)s2 * F_OUT + c0];
        float4 h3 = *(const float4*)&h[(size_t)s3 * F_OUT + c0];
        float a0 = expf(lrelu(e0 + adn) - mx) / den;
        float a1 = expf(lrelu(e1 + adn) - mx) / den;
        float a2 = expf(lrelu(e2 + adn) - mx) / den;
        float a3 = expf(lrelu(e3 + adn) - mx) / den;
        acc.x += a0 * h0.x + a1 * h1.x + a2 * h2.x + a3 * h3.x;
        acc.y += a0 * h0.y + a1 * h1.y + a2 * h2.y + a3 * h3.y;
        acc.z += a0 * h0.z + a1 * h1.z + a2 * h2.z + a3 * h3.z;
        acc.w += a0 * h0.w + a1 * h1.w + a2 * h2.w + a3 * h3.w;
    }
    for (; i < deg; ++i) {
        int s = ssrc[beg + i];
        float a0 = expf(lrelu(a_s[s * NH + hd] + adn) - mx) / den;
        float4 hv = *(const float4*)&h[(size_t)s * F_OUT + c0];
        acc.x += a0 * hv.x; acc.y += a0 * hv.y; acc.z += a0 * hv.z; acc.w += a0 * hv.w;
    }
    float4 bv = *(const float4*)&bias[c0];
    float4 ov;
    ov.x = fmaxf(acc.x + bv.x, 0.f);
    ov.y = fmaxf(acc.y + bv.y, 0.f);
    ov.z = fmaxf(acc.z + bv.z, 0.f);
    ov.w = fmaxf(acc.w + bv.w, 0.f);
    *(float4*)&out[(size_t)n * F_OUT + c0] = ov;
}

// ---------------------------------------------------------------------------
// graph histogram + fused mean-pool + linear head
// ---------------------------------------------------------------------------
__global__ void ghist_kernel(const int* __restrict__ batch, int* __restrict__ gcnt)
{
    int n = blockIdx.x * blockDim.x + threadIdx.x;
    if (n < N_NODES) atomicAdd(&gcnt[batch[n]], 1);
}

__global__ __launch_bounds__(256) void pool_kernel(const float* __restrict__ x,
                                                   const int* __restrict__ gcnt,
                                                   const float* __restrict__ lin_w,
                                                   const float* __restrict__ lin_b,
                                                   float* __restrict__ out)
{
    const int g = blockIdx.x;
    const int t = threadIdx.x;
    __shared__ int s_start;
    if (t == 0) {
        int s = 0;
        for (int i = 0; i < g; ++i) s += gcnt[i];
        s_start = s;
    }
    __syncthreads();
    const int start = s_start;
    const int cnt = gcnt[g];
    float acc = 0.f;
    for (int i = 0; i < cnt; ++i) acc += x[(size_t)(start + i) * F_OUT + t];
    float p = acc / fmaxf((float)cnt, 1.f);
    float v = p * lin_w[t];
    __shared__ float red[256];
    red[t] = v;
    __syncthreads();
    for (int o = 128; o > 0; o >>= 1) {
        if (t < o) red[t] += red[t + o];
        __syncthreads();
    }
    if (t == 0) out[g] = red[0] + lin_b[0];
}

// ---------------------------------------------------------------------------
extern "C" void kernel_launch(void* const* d_in, const int* in_sizes, int n_in,
                              void* d_out, int out_size, void* d_ws, size_t ws_size,
                              hipStream_t stream)
{
    const float* x      = (const float*)d_in[0];
    const int*   ei     = (const int*)  d_in[1];
    const int*   batch  = (const int*)  d_in[2];
    const float* W1     = (const float*)d_in[3];
    const float* att_s1 = (const float*)d_in[4];
    const float* att_d1 = (const float*)d_in[5];
    const float* b1     = (const float*)d_in[6];
    const float* W2     = (const float*)d_in[7];
    const float* att_s2 = (const float*)d_in[8];
    const float* att_d2 = (const float*)d_in[9];
    const float* b2     = (const float*)d_in[10];
    const float* lin_w  = (const float*)d_in[11];
    const float* lin_b  = (const float*)d_in[12];
    float* out = (float*)d_out;

    const int Kp1 = 1312;   // 1300 padded to x32
    const int Kp2 = 256;

    size_t off = 0;
    auto carve = [&](size_t bytes) -> void* {
        void* p = (char*)d_ws + off;
        off += (bytes + 255) & ~(size_t)255;
        return p;
    };
    float* hA     = (float*)carve((size_t)N_NODES * F_OUT * 4);
    float* hB     = (float*)carve((size_t)N_NODES * F_OUT * 4);
    float* a_s    = (float*)carve((size_t)N_NODES * NH * 4);
    float* a_d    = (float*)carve((size_t)N_NODES * NH * 4);
    int*   deg    = (int*)  carve((size_t)(N_NODES + 1) * 4);
    int*   rowptr = (int*)  carve((size_t)(N_NODES + 1) * 4);
    int*   cursor = (int*)  carve((size_t)N_NODES * 4);
    int*   ssrc   = (int*)  carve((size_t)N_EDGES * 4);
    int*   gcnt   = (int*)  carve((size_t)NG * 4);
    short* Bt1h   = (short*)carve((size_t)F_OUT * Kp1 * 2);
    short* Bt1l   = (short*)carve((size_t)F_OUT * Kp1 * 2);
    short* Bt2h   = (short*)carve((size_t)F_OUT * Kp2 * 2);
    short* Bt2l   = (short*)carve((size_t)F_OUT * Kp2 * 2);
    (void)ws_size; (void)n_in; (void)in_sizes; (void)out_size;

    // ---- CSR build + weight pre-split ----
    hipMemsetAsync(deg, 0, (size_t)(N_NODES + 1) * 4, stream);
    hipMemsetAsync(gcnt, 0, (size_t)NG * 4, stream);
    hist_kernel<<<(N_EDGES + 255) / 256, 256, 0, stream>>>(ei, deg);
    scan_kernel<<<1, 1024, 0, stream>>>(deg, rowptr);
    hipMemcpyAsync(cursor, rowptr, (size_t)N_NODES * 4, hipMemcpyDeviceToDevice, stream);
    scatter_kernel<<<(N_EDGES + 255) / 256, 256, 0, stream>>>(ei, cursor, ssrc);
    ghist_kernel<<<(N_NODES + 255) / 256, 256, 0, stream>>>(batch, gcnt);
    wsplit_kernel<<<(F_OUT * Kp1 + 255) / 256, 256, 0, stream>>>(W1, Bt1h, Bt1l, F_IN, Kp1);
    wsplit_kernel<<<(F_OUT * Kp2 + 255) / 256, 256, 0, stream>>>(W2, Bt2h, Bt2l, F_OUT, Kp2);

    const int gblocks = N_NODES / 64;  // 625
    const int ablocks = N_NODES / 4;   // 10000 (wave per node)

    // ---- layer 1 ----
    gemm_mfma_kernel<<<gblocks, 256, 0, stream>>>(x, Bt1h, Bt1l, hA, F_IN, Kp1);
    attn_coef_kernel<<<N_NODES, 256, 0, stream>>>(hA, att_s1, att_d1, a_s, a_d);
    agg_kernel<<<ablocks, 256, 0, stream>>>(hA, a_s, a_d, rowptr, ssrc, b1, hB);

    // ---- layer 2 ----
    gemm_mfma_kernel<<<gblocks, 256, 0, stream>>>(hB, Bt2h, Bt2l, hA, F_OUT, Kp2);
    attn_coef_kernel<<<N_NODES, 256, 0, stream>>>(hA, att_s2, att_d2, a_s, a_d);
    agg_kernel<<<ablocks, 256, 0, stream>>>(hA, a_s, a_d, rowptr, ssrc, b2, hB);

    // ---- pool + head ----
    pool_kernel<<<NG, 256, 0, stream>>>(hB, gcnt, lin_w, lin_b, out);
}